// Round 1
// baseline (4090.986 us; speedup 1.0000x reference)
//
#include <hip/hip_runtime.h>
#include <cstddef>

#define NN  100000
#define NE  600000
#define NG  4096
#define DIN 73
#define DE  101
#define DD  128
#define DD2 256

__device__ __forceinline__ void fadd_atomic(float* p, float v) {
    unsafeAtomicAdd(p, v);  // HW global_atomic_add_f32
}

__device__ __forceinline__ void fma4x4(const float4 av, const float4 b0, const float4 b1,
                                       const float4 b2, const float4 b3, float* acc) {
    acc[0] = fmaf(av.x, b0.x, fmaf(av.y, b1.x, fmaf(av.z, b2.x, fmaf(av.w, b3.x, acc[0]))));
    acc[1] = fmaf(av.x, b0.y, fmaf(av.y, b1.y, fmaf(av.z, b2.y, fmaf(av.w, b3.y, acc[1]))));
    acc[2] = fmaf(av.x, b0.z, fmaf(av.y, b1.z, fmaf(av.z, b2.z, fmaf(av.w, b3.z, acc[2]))));
    acc[3] = fmaf(av.x, b0.w, fmaf(av.y, b1.w, fmaf(av.z, b2.w, fmaf(av.w, b3.w, acc[3]))));
}

// h = x @ W_emb + b_emb   [N,73]x[73,128]
__global__ __launch_bounds__(128) void embed_kernel(
    const float* __restrict__ x, const float* __restrict__ W,
    const float* __restrict__ b, float* __restrict__ h)
{
    __shared__ float xs[4][DIN];
    const int n0 = blockIdx.x * 4;
    const int d  = threadIdx.x;
    for (int idx = d; idx < 4 * DIN; idx += 128) {
        int r = idx / DIN, c = idx - r * DIN;
        xs[r][c] = x[(size_t)n0 * DIN + idx];
    }
    __syncthreads();
    float bb = b[d];
    float a0 = bb, a1 = bb, a2 = bb, a3 = bb;
    for (int k = 0; k < DIN; ++k) {
        float w = W[k * DD + d];
        a0 = fmaf(xs[0][k], w, a0);
        a1 = fmaf(xs[1][k], w, a1);
        a2 = fmaf(xs[2][k], w, a2);
        a3 = fmaf(xs[3][k], w, a3);
    }
    h[(size_t)(n0 + 0) * DD + d] = a0;
    h[(size_t)(n0 + 1) * DD + d] = a1;
    h[(size_t)(n0 + 2) * DD + d] = a2;
    h[(size_t)(n0 + 3) * DD + d] = a3;
}

__global__ void copy_kernel(float* __restrict__ dstp, const float* __restrict__ srcp, int n4) {
    int i = blockIdx.x * blockDim.x + threadIdx.x;
    const int stride = gridDim.x * blockDim.x;
    const float4* s = (const float4*)srcp;
    float4* d = (float4*)dstp;
    for (; i < n4; i += stride) d[i] = s[i];
}

// e = ea @ We + be ; msg = relu(h[src] + e) ; z[dst] += msg   (z pre-initialized to h)
// tile: 32 edges x 128 cols, 256 threads = 8 edge-groups x 32 col-groups, thread = 4x4
__global__ __launch_bounds__(256) void edge_kernel(
    const float* __restrict__ ea, const float* __restrict__ We,
    const float* __restrict__ be, const int* __restrict__ src,
    const int* __restrict__ dst, const float* __restrict__ h,
    float* __restrict__ z)
{
    __shared__ float eas[32][104];   // stride 104 -> 16B-aligned rows for ds_read_b128
    const int e0  = blockIdx.x * 32;
    const int tid = threadIdx.x;
    for (int idx = tid; idx < 32 * DE; idx += 256) {
        int r = idx / DE, c = idx - r * DE;
        eas[r][c] = ea[(size_t)e0 * DE + idx];
    }
    __syncthreads();
    const int cg = tid & 31, eg = tid >> 5;
    const int c0 = cg * 4, r0 = eg * 4;
    float acc[4][4] = {};
    #pragma unroll 5
    for (int k4 = 0; k4 < 25; ++k4) {          // k = 0..99
        const int k = k4 * 4;
        const float4 b0 = *(const float4*)&We[(k + 0) * DD + c0];
        const float4 b1 = *(const float4*)&We[(k + 1) * DD + c0];
        const float4 b2 = *(const float4*)&We[(k + 2) * DD + c0];
        const float4 b3 = *(const float4*)&We[(k + 3) * DD + c0];
        #pragma unroll
        for (int r = 0; r < 4; ++r) {
            const float4 av = *(const float4*)&eas[r0 + r][k];
            fma4x4(av, b0, b1, b2, b3, acc[r]);
        }
    }
    {   // tail k = 100 (We has only 101 rows -- no OOB)
        const float4 bt = *(const float4*)&We[100 * DD + c0];
        #pragma unroll
        for (int r = 0; r < 4; ++r) {
            const float av = eas[r0 + r][100];
            acc[r][0] = fmaf(av, bt.x, acc[r][0]);
            acc[r][1] = fmaf(av, bt.y, acc[r][1]);
            acc[r][2] = fmaf(av, bt.z, acc[r][2]);
            acc[r][3] = fmaf(av, bt.w, acc[r][3]);
        }
    }
    const float4 bev = *(const float4*)&be[c0];
    #pragma unroll
    for (int r = 0; r < 4; ++r) {
        const int e = e0 + r0 + r;
        const int sn = src[e], dn = dst[e];
        const float4 hv = *(const float4*)&h[(size_t)sn * DD + c0];
        float v0 = fmaxf(acc[r][0] + bev.x + hv.x, 0.f);
        float v1 = fmaxf(acc[r][1] + bev.y + hv.y, 0.f);
        float v2 = fmaxf(acc[r][2] + bev.z + hv.z, 0.f);
        float v3 = fmaxf(acc[r][3] + bev.w + hv.w, 0.f);
        float* zp = &z[(size_t)dn * DD + c0];
        fadd_atomic(zp + 0, v0);
        fadd_atomic(zp + 1, v1);
        fadd_atomic(zp + 2, v2);
        fadd_atomic(zp + 3, v3);
    }
}

// y1 = z @ W1 + b1  [N,128]x[128,256]; accumulate column sums/sumsq for BN
// tile: 16 rows x 256 cols, 256 threads = 4 row-groups x 64 col-groups
__global__ __launch_bounds__(256) void mlp1_kernel(
    const float* __restrict__ z, const float* __restrict__ W1,
    const float* __restrict__ bias, float* __restrict__ y1,
    float* __restrict__ s1, float* __restrict__ sq1)
{
    const int row0 = blockIdx.x * 16;
    const int tid  = threadIdx.x;
    const int cg = tid & 63, rg = tid >> 6;
    const int c0 = cg * 4, r0 = rg * 4;
    float acc[4][4] = {};
    #pragma unroll 4
    for (int k4 = 0; k4 < 32; ++k4) {
        const int k = k4 * 4;
        const float4 b0 = *(const float4*)&W1[(k + 0) * DD2 + c0];
        const float4 b1 = *(const float4*)&W1[(k + 1) * DD2 + c0];
        const float4 b2 = *(const float4*)&W1[(k + 2) * DD2 + c0];
        const float4 b3 = *(const float4*)&W1[(k + 3) * DD2 + c0];
        #pragma unroll
        for (int r = 0; r < 4; ++r) {
            const float4 av = *(const float4*)&z[(size_t)(row0 + r0 + r) * DD + k];
            fma4x4(av, b0, b1, b2, b3, acc[r]);
        }
    }
    const float4 bb = *(const float4*)&bias[c0];
    float ps[4] = {}, pq[4] = {};
    #pragma unroll
    for (int r = 0; r < 4; ++r) {
        float4 v;
        v.x = acc[r][0] + bb.x; v.y = acc[r][1] + bb.y;
        v.z = acc[r][2] + bb.z; v.w = acc[r][3] + bb.w;
        *(float4*)&y1[(size_t)(row0 + r0 + r) * DD2 + c0] = v;
        ps[0] += v.x; pq[0] += v.x * v.x;
        ps[1] += v.y; pq[1] += v.y * v.y;
        ps[2] += v.z; pq[2] += v.z * v.z;
        ps[3] += v.w; pq[3] += v.w * v.w;
    }
    __shared__ float redS[4][DD2];
    __shared__ float redQ[4][DD2];
    #pragma unroll
    for (int i = 0; i < 4; ++i) { redS[rg][c0 + i] = ps[i]; redQ[rg][c0 + i] = pq[i]; }
    __syncthreads();
    if (tid < 64) {
        #pragma unroll
        for (int i = 0; i < 4; ++i) {
            int c = tid * 4 + i;
            float s = redS[0][c] + redS[1][c] + redS[2][c] + redS[3][c];
            float q = redQ[0][c] + redQ[1][c] + redQ[2][c] + redQ[3][c];
            fadd_atomic(&s1[c], s);
            fadd_atomic(&sq1[c], q);
        }
    }
}

// a = g*rsqrt(var+eps), c = bb - mean*a
__global__ void finalize_kernel(const float* __restrict__ s, const float* __restrict__ sq,
                                const float* __restrict__ g, const float* __restrict__ bb,
                                float* __restrict__ a, float* __restrict__ c,
                                int dim, float invN)
{
    int d = blockIdx.x * blockDim.x + threadIdx.x;
    if (d >= dim) return;
    float m  = s[d] * invN;
    float v  = sq[d] * invN - m * m;
    float rs = rsqrtf(v + 1e-5f);
    float ai = g[d] * rs;
    a[d] = ai;
    c[d] = bb[d] - m * ai;
}

// y2 = relu(bn1(y1)) @ W2 + b2 ; BN stats for y2.  tile 32x128, 256 thr = 8x32
__global__ __launch_bounds__(256) void mlp2_kernel(
    const float* __restrict__ y1, const float* __restrict__ a1, const float* __restrict__ c1,
    const float* __restrict__ W2, const float* __restrict__ bias,
    float* __restrict__ y2, float* __restrict__ s2, float* __restrict__ sq2)
{
    __shared__ float ys[32][DD2];   // bn1+relu applied once at stage time
    const int row0 = blockIdx.x * 32;
    const int tid  = threadIdx.x;
    for (int idx = tid; idx < 32 * DD2; idx += 256) {
        int r = idx >> 8, k = idx & 255;
        float v = fmaf(y1[(size_t)row0 * DD2 + idx], a1[k], c1[k]);
        ys[r][k] = fmaxf(v, 0.f);
    }
    __syncthreads();
    const int cg = tid & 31, rg = tid >> 5;
    const int c0 = cg * 4, r0 = rg * 4;
    float acc[4][4] = {};
    #pragma unroll 4
    for (int k4 = 0; k4 < 64; ++k4) {
        const int k = k4 * 4;
        const float4 b0 = *(const float4*)&W2[(k + 0) * DD + c0];
        const float4 b1 = *(const float4*)&W2[(k + 1) * DD + c0];
        const float4 b2 = *(const float4*)&W2[(k + 2) * DD + c0];
        const float4 b3 = *(const float4*)&W2[(k + 3) * DD + c0];
        #pragma unroll
        for (int r = 0; r < 4; ++r) {
            const float4 av = *(const float4*)&ys[r0 + r][k];
            fma4x4(av, b0, b1, b2, b3, acc[r]);
        }
    }
    const float4 bb = *(const float4*)&bias[c0];
    float ps[4] = {}, pq[4] = {};
    #pragma unroll
    for (int r = 0; r < 4; ++r) {
        float4 v;
        v.x = acc[r][0] + bb.x; v.y = acc[r][1] + bb.y;
        v.z = acc[r][2] + bb.z; v.w = acc[r][3] + bb.w;
        *(float4*)&y2[(size_t)(row0 + r0 + r) * DD + c0] = v;
        ps[0] += v.x; pq[0] += v.x * v.x;
        ps[1] += v.y; pq[1] += v.y * v.y;
        ps[2] += v.z; pq[2] += v.z * v.z;
        ps[3] += v.w; pq[3] += v.w * v.w;
    }
    __shared__ float redS[8][DD];
    __shared__ float redQ[8][DD];
    #pragma unroll
    for (int i = 0; i < 4; ++i) { redS[rg][c0 + i] = ps[i]; redQ[rg][c0 + i] = pq[i]; }
    __syncthreads();
    if (tid < DD) {
        float s = 0.f, q = 0.f;
        #pragma unroll
        for (int gi = 0; gi < 8; ++gi) { s += redS[gi][tid]; q += redQ[gi][tid]; }
        fadd_atomic(&s2[tid], s);
        fadd_atomic(&sq2[tid], q);
    }
}

// h = relu(bn(y2)) in place (layer 0)
__global__ void bn_relu_kernel(float* __restrict__ y2h, const float* __restrict__ a2,
                               const float* __restrict__ c2, int n4)
{
    int i = blockIdx.x * blockDim.x + threadIdx.x;
    const int stride = gridDim.x * blockDim.x;
    float4* p = (float4*)y2h;
    for (; i < n4; i += stride) {
        float4 v = p[i];
        const int d0 = (i & 31) * 4;
        v.x = fmaxf(fmaf(v.x, a2[d0 + 0], c2[d0 + 0]), 0.f);
        v.y = fmaxf(fmaf(v.y, a2[d0 + 1], c2[d0 + 1]), 0.f);
        v.z = fmaxf(fmaf(v.z, a2[d0 + 2], c2[d0 + 2]), 0.f);
        v.w = fmaxf(fmaf(v.w, a2[d0 + 3], c2[d0 + 3]), 0.f);
        p[i] = v;
    }
}

// last layer: h = bn(y2) (no relu) fused with mean-pool accumulation
__global__ void bn_pool_kernel(const float* __restrict__ y2, const float* __restrict__ a2,
                               const float* __restrict__ c2, const int* __restrict__ batch,
                               float* __restrict__ out)
{
    int i = blockIdx.x * blockDim.x + threadIdx.x;
    const int stride = gridDim.x * blockDim.x;
    const float4* p = (const float4*)y2;
    for (; i < NN * (DD / 4); i += stride) {
        float4 v = p[i];
        const int n  = i >> 5;
        const int d0 = (i & 31) * 4;
        const int g  = batch[n];
        float* op = &out[(size_t)g * DD + d0];
        fadd_atomic(op + 0, fmaf(v.x, a2[d0 + 0], c2[d0 + 0]));
        fadd_atomic(op + 1, fmaf(v.y, a2[d0 + 1], c2[d0 + 1]));
        fadd_atomic(op + 2, fmaf(v.z, a2[d0 + 2], c2[d0 + 2]));
        fadd_atomic(op + 3, fmaf(v.w, a2[d0 + 3], c2[d0 + 3]));
    }
}

__global__ void counts_kernel(const int* __restrict__ batch, float* __restrict__ counts) {
    int i = blockIdx.x * blockDim.x + threadIdx.x;
    if (i < NN) fadd_atomic(&counts[batch[i]], 1.0f);
}

__global__ void div_kernel(float* __restrict__ out, const float* __restrict__ counts) {
    int i = blockIdx.x * blockDim.x + threadIdx.x;   // < NG*DD
    float c = counts[i >> 7];
    out[i] = out[i] / fmaxf(c, 1.0f);
}

extern "C" void kernel_launch(void* const* d_in, const int* in_sizes, int n_in,
                              void* d_out, int out_size, void* d_ws, size_t ws_size,
                              hipStream_t stream)
{
    (void)in_sizes; (void)n_in; (void)out_size; (void)ws_size;
    const float* x     = (const float*)d_in[0];
    const float* ea    = (const float*)d_in[1];
    const int*   src   = (const int*)d_in[2];
    const int*   dst   = (const int*)d_in[3];
    const int*   batch = (const int*)d_in[4];
    const float* W_emb = (const float*)d_in[5];
    const float* b_emb = (const float*)d_in[6];

    float* zbuf = (float*)d_ws;                       // [N,128]
    float* y1   = zbuf + (size_t)NN * DD;             // [N,256]
    float* hbuf = y1 + (size_t)NN * DD2;              // [N,128] (h, then y2 in place)
    float* st   = hbuf + (size_t)NN * DD;             // stats block
    float* s1 = st,        *sq1 = st + 256, *a1 = st + 512,  *c1 = st + 768;
    float* s2 = st + 1024, *sq2 = st + 1152, *a2 = st + 1280, *c2 = st + 1408;
    float* counts = st + 1536;                        // [4096]
    float* out = (float*)d_out;

    embed_kernel<<<NN / 4, 128, 0, stream>>>(x, W_emb, b_emb, hbuf);

    for (int layer = 0; layer < 2; ++layer) {
        const float* const* L = (const float* const*)(d_in + 7 + layer * 10);
        const float* We = L[0]; const float* be  = L[1];
        const float* W1 = L[2]; const float* b1  = L[3];
        const float* g1 = L[4]; const float* bb1 = L[5];
        const float* W2 = L[6]; const float* b2  = L[7];
        const float* go = L[8]; const float* bo  = L[9];

        copy_kernel<<<2048, 256, 0, stream>>>(zbuf, hbuf, NN * DD / 4);
        edge_kernel<<<NE / 32, 256, 0, stream>>>(ea, We, be, src, dst, hbuf, zbuf);
        hipMemsetAsync(s1, 0, 512 * sizeof(float), stream);   // s1+sq1
        hipMemsetAsync(s2, 0, 256 * sizeof(float), stream);   // s2+sq2
        mlp1_kernel<<<NN / 16, 256, 0, stream>>>(zbuf, W1, b1, y1, s1, sq1);
        finalize_kernel<<<1, 256, 0, stream>>>(s1, sq1, g1, bb1, a1, c1, DD2, 1.0f / NN);
        mlp2_kernel<<<NN / 32, 256, 0, stream>>>(y1, a1, c1, W2, b2, hbuf, s2, sq2);
        finalize_kernel<<<1, 128, 0, stream>>>(s2, sq2, go, bo, a2, c2, DD, 1.0f / NN);
        if (layer == 0) {
            bn_relu_kernel<<<2048, 256, 0, stream>>>(hbuf, a2, c2, NN * DD / 4);
        } else {
            hipMemsetAsync(d_out, 0, (size_t)NG * DD * sizeof(float), stream);
            hipMemsetAsync(counts, 0, NG * sizeof(float), stream);
            counts_kernel<<<(NN + 255) / 256, 256, 0, stream>>>(batch, counts);
            bn_pool_kernel<<<2048, 256, 0, stream>>>(hbuf, a2, c2, batch, out);
            div_kernel<<<NG * DD / 256, 256, 0, stream>>>(out, counts);
        }
    }
}

// Round 2
// 2986.453 us; speedup vs baseline: 1.3698x; 1.3698x over previous
//
#include <hip/hip_runtime.h>
#include <cstddef>

#define NN  100000
#define NE  600000
#define NG  4096
#define DIN 73
#define DE  101
#define DD  128
#define DD2 256

typedef unsigned int uint;
typedef unsigned short ushort;

__device__ __forceinline__ void fadd_atomic(float* p, float v) {
    unsafeAtomicAdd(p, v);  // HW global_atomic_add_f32
}

__device__ __forceinline__ ushort f2bf(float f) {   // RNE f32->bf16
    uint u = __float_as_uint(f);
    uint r = (u + 0x7fffu + ((u >> 16) & 1u)) >> 16;
    return (ushort)r;
}

__device__ __forceinline__ void fma4x4(const float4 av, const float4 b0, const float4 b1,
                                       const float4 b2, const float4 b3, float* acc) {
    acc[0] = fmaf(av.x, b0.x, fmaf(av.y, b1.x, fmaf(av.z, b2.x, fmaf(av.w, b3.x, acc[0]))));
    acc[1] = fmaf(av.x, b0.y, fmaf(av.y, b1.y, fmaf(av.z, b2.y, fmaf(av.w, b3.y, acc[1]))));
    acc[2] = fmaf(av.x, b0.z, fmaf(av.y, b1.z, fmaf(av.z, b2.z, fmaf(av.w, b3.z, acc[2]))));
    acc[3] = fmaf(av.x, b0.w, fmaf(av.y, b1.w, fmaf(av.z, b2.w, fmaf(av.w, b3.w, acc[3]))));
}

// ---------------- CSR build (once per call; graph identical across layers) ---

__global__ void hist_kernel(const int* __restrict__ dst, int* __restrict__ deg) {
    int e = blockIdx.x * blockDim.x + threadIdx.x;
    if (e < NE) atomicAdd(&deg[dst[e]], 1);
}

// chunk = 1024 ints per block (256 thr x 4); writes per-element exclusive-in-chunk
__global__ __launch_bounds__(256) void scan_chunk_kernel(
    const int* __restrict__ deg, int* __restrict__ offs, int* __restrict__ csums)
{
    const int b = blockIdx.x, t = threadIdx.x;
    const int base = b * 1024 + t * 4;
    int v[4];
    #pragma unroll
    for (int i = 0; i < 4; ++i) v[i] = (base + i < NN) ? deg[base + i] : 0;
    int tsum = v[0] + v[1] + v[2] + v[3];
    const int lane = t & 63, w = t >> 6;
    int x = tsum;
    #pragma unroll
    for (int d = 1; d < 64; d <<= 1) {
        int y = __shfl_up(x, d, 64);
        if (lane >= d) x += y;
    }
    __shared__ int wsum[4];
    if (lane == 63) wsum[w] = x;
    __syncthreads();
    int woff = 0;
    for (int i = 0; i < w; ++i) woff += wsum[i];
    int run = woff + x - tsum;   // exclusive prefix of this thread within chunk
    #pragma unroll
    for (int i = 0; i < 4; ++i) {
        if (base + i < NN) offs[base + i] = run;
        run += v[i];
    }
    if (t == 255) csums[b] = woff + x;   // chunk total
}

__global__ void scan_tops_kernel(int* __restrict__ csums, int* __restrict__ offs, int nchunks) {
    if (threadIdx.x == 0 && blockIdx.x == 0) {
        int run = 0;
        for (int i = 0; i < nchunks; ++i) { int c = csums[i]; csums[i] = run; run += c; }
        offs[NN] = run;   // == NE
    }
}

__global__ void scan_add_kernel(int* __restrict__ offs, const int* __restrict__ csums) {
    int i = blockIdx.x * blockDim.x + threadIdx.x;
    if (i < NN) offs[i] += csums[i >> 10];
}

__global__ void scatter_kernel(const int* __restrict__ dst, const int* __restrict__ offs,
                               int* __restrict__ cursor, int* __restrict__ csr)
{
    int e = blockIdx.x * blockDim.x + threadIdx.x;
    if (e >= NE) return;
    int d = dst[e];
    int pos = offs[d] + atomicAdd(&cursor[d], 1);
    csr[pos] = e;
}

// gstart[g] = first node index with batch >= g ; gstart[NG] = NN (batch is sorted)
__global__ void gstart_kernel(const int* __restrict__ batch, int* __restrict__ gstart) {
    int n = blockIdx.x * blockDim.x + threadIdx.x;
    if (n > NN) return;
    if (n == NN) {
        for (int g = batch[NN - 1] + 1; g <= NG; ++g) gstart[g] = NN;
        return;
    }
    int b = batch[n];
    int pb = (n == 0) ? -1 : batch[n - 1];
    for (int g = pb + 1; g <= b; ++g) gstart[g] = n;
}

// ---------------- forward kernels ------------------------------------------

// h = x @ W_emb + b_emb   [N,73]x[73,128]
__global__ __launch_bounds__(128) void embed_kernel(
    const float* __restrict__ x, const float* __restrict__ W,
    const float* __restrict__ b, float* __restrict__ h)
{
    __shared__ float xs[4][DIN];
    const int n0 = blockIdx.x * 4;
    const int d  = threadIdx.x;
    for (int idx = d; idx < 4 * DIN; idx += 128) {
        int r = idx / DIN, c = idx - r * DIN;
        xs[r][c] = x[(size_t)n0 * DIN + idx];
    }
    __syncthreads();
    float bb = b[d];
    float a0 = bb, a1 = bb, a2 = bb, a3 = bb;
    for (int k = 0; k < DIN; ++k) {
        float w = W[k * DD + d];
        a0 = fmaf(xs[0][k], w, a0);
        a1 = fmaf(xs[1][k], w, a1);
        a2 = fmaf(xs[2][k], w, a2);
        a3 = fmaf(xs[3][k], w, a3);
    }
    h[(size_t)(n0 + 0) * DD + d] = a0;
    h[(size_t)(n0 + 1) * DD + d] = a1;
    h[(size_t)(n0 + 2) * DD + d] = a2;
    h[(size_t)(n0 + 3) * DD + d] = a3;
}

// e = ea @ We + be ; msg = relu(h[src] + e) -> bf16 store (edge order, no atomics)
__global__ __launch_bounds__(256) void edge_gemm_kernel(
    const float* __restrict__ ea, const float* __restrict__ We,
    const float* __restrict__ be, const int* __restrict__ src,
    const float* __restrict__ h, ushort* __restrict__ msgb)
{
    __shared__ float eas[32][104];
    const int e0  = blockIdx.x * 32;
    const int tid = threadIdx.x;
    for (int idx = tid; idx < 32 * DE; idx += 256) {
        int r = idx / DE, c = idx - r * DE;
        eas[r][c] = ea[(size_t)e0 * DE + idx];
    }
    __syncthreads();
    const int cg = tid & 31, eg = tid >> 5;
    const int c0 = cg * 4, r0 = eg * 4;
    float acc[4][4] = {};
    #pragma unroll 5
    for (int k4 = 0; k4 < 25; ++k4) {
        const int k = k4 * 4;
        const float4 b0 = *(const float4*)&We[(k + 0) * DD + c0];
        const float4 b1 = *(const float4*)&We[(k + 1) * DD + c0];
        const float4 b2 = *(const float4*)&We[(k + 2) * DD + c0];
        const float4 b3 = *(const float4*)&We[(k + 3) * DD + c0];
        #pragma unroll
        for (int r = 0; r < 4; ++r) {
            const float4 av = *(const float4*)&eas[r0 + r][k];
            fma4x4(av, b0, b1, b2, b3, acc[r]);
        }
    }
    {   // tail k = 100
        const float4 bt = *(const float4*)&We[100 * DD + c0];
        #pragma unroll
        for (int r = 0; r < 4; ++r) {
            const float av = eas[r0 + r][100];
            acc[r][0] = fmaf(av, bt.x, acc[r][0]);
            acc[r][1] = fmaf(av, bt.y, acc[r][1]);
            acc[r][2] = fmaf(av, bt.z, acc[r][2]);
            acc[r][3] = fmaf(av, bt.w, acc[r][3]);
        }
    }
    const float4 bev = *(const float4*)&be[c0];
    #pragma unroll
    for (int r = 0; r < 4; ++r) {
        const int e = e0 + r0 + r;
        const int sn = src[e];
        const float4 hv = *(const float4*)&h[(size_t)sn * DD + c0];
        ushort4 o;
        o.x = f2bf(fmaxf(acc[r][0] + bev.x + hv.x, 0.f));
        o.y = f2bf(fmaxf(acc[r][1] + bev.y + hv.y, 0.f));
        o.z = f2bf(fmaxf(acc[r][2] + bev.z + hv.z, 0.f));
        o.w = f2bf(fmaxf(acc[r][3] + bev.w + hv.w, 0.f));
        *(ushort4*)&msgb[(size_t)e * DD + c0] = o;
    }
}

// z[n] = h[n] + sum_{e in in(n)} msg[e]   (one wave per node, lane = 2 cols)
__global__ __launch_bounds__(256) void agg_kernel(
    const int* __restrict__ offs, const int* __restrict__ csr,
    const ushort* __restrict__ msgb, const float* __restrict__ h,
    float* __restrict__ z)
{
    const int n = blockIdx.x * 4 + (threadIdx.x >> 6);
    if (n >= NN) return;
    const int lane = threadIdx.x & 63;
    const int s = offs[n], t = offs[n + 1];
    float a0 = 0.f, a1 = 0.f;
    for (int i = s; i < t; ++i) {
        const int e = csr[i];
        const uint mv = *(const uint*)&msgb[(size_t)e * DD + lane * 2];
        a0 += __uint_as_float(mv << 16);
        a1 += __uint_as_float(mv & 0xffff0000u);
    }
    const float2 hv = *(const float2*)&h[(size_t)n * DD + lane * 2];
    float2 o; o.x = hv.x + a0; o.y = hv.y + a1;
    *(float2*)&z[(size_t)n * DD + lane * 2] = o;
}

// y1 = z @ W1 + b1  [N,128]x[128,256] + BN column stats
__global__ __launch_bounds__(256) void mlp1_kernel(
    const float* __restrict__ z, const float* __restrict__ W1,
    const float* __restrict__ bias, float* __restrict__ y1,
    float* __restrict__ s1, float* __restrict__ sq1)
{
    const int row0 = blockIdx.x * 16;
    const int tid  = threadIdx.x;
    const int cg = tid & 63, rg = tid >> 6;
    const int c0 = cg * 4, r0 = rg * 4;
    float acc[4][4] = {};
    #pragma unroll 4
    for (int k4 = 0; k4 < 32; ++k4) {
        const int k = k4 * 4;
        const float4 b0 = *(const float4*)&W1[(k + 0) * DD2 + c0];
        const float4 b1 = *(const float4*)&W1[(k + 1) * DD2 + c0];
        const float4 b2 = *(const float4*)&W1[(k + 2) * DD2 + c0];
        const float4 b3 = *(const float4*)&W1[(k + 3) * DD2 + c0];
        #pragma unroll
        for (int r = 0; r < 4; ++r) {
            const float4 av = *(const float4*)&z[(size_t)(row0 + r0 + r) * DD + k];
            fma4x4(av, b0, b1, b2, b3, acc[r]);
        }
    }
    const float4 bb = *(const float4*)&bias[c0];
    float ps[4] = {}, pq[4] = {};
    #pragma unroll
    for (int r = 0; r < 4; ++r) {
        float4 v;
        v.x = acc[r][0] + bb.x; v.y = acc[r][1] + bb.y;
        v.z = acc[r][2] + bb.z; v.w = acc[r][3] + bb.w;
        *(float4*)&y1[(size_t)(row0 + r0 + r) * DD2 + c0] = v;
        ps[0] += v.x; pq[0] += v.x * v.x;
        ps[1] += v.y; pq[1] += v.y * v.y;
        ps[2] += v.z; pq[2] += v.z * v.z;
        ps[3] += v.w; pq[3] += v.w * v.w;
    }
    __shared__ float redS[4][DD2];
    __shared__ float redQ[4][DD2];
    #pragma unroll
    for (int i = 0; i < 4; ++i) { redS[rg][c0 + i] = ps[i]; redQ[rg][c0 + i] = pq[i]; }
    __syncthreads();
    if (tid < 64) {
        #pragma unroll
        for (int i = 0; i < 4; ++i) {
            int c = tid * 4 + i;
            float s = redS[0][c] + redS[1][c] + redS[2][c] + redS[3][c];
            float q = redQ[0][c] + redQ[1][c] + redQ[2][c] + redQ[3][c];
            fadd_atomic(&s1[c], s);
            fadd_atomic(&sq1[c], q);
        }
    }
}

__global__ void finalize_kernel(const float* __restrict__ s, const float* __restrict__ sq,
                                const float* __restrict__ g, const float* __restrict__ bb,
                                float* __restrict__ a, float* __restrict__ c,
                                int dim, float invN)
{
    int d = blockIdx.x * blockDim.x + threadIdx.x;
    if (d >= dim) return;
    float m  = s[d] * invN;
    float v  = sq[d] * invN - m * m;
    float rs = rsqrtf(v + 1e-5f);
    float ai = g[d] * rs;
    a[d] = ai;
    c[d] = bb[d] - m * ai;
}

// y2 = relu(bn1(y1)) @ W2 + b2 + BN column stats
__global__ __launch_bounds__(256) void mlp2_kernel(
    const float* __restrict__ y1, const float* __restrict__ a1, const float* __restrict__ c1,
    const float* __restrict__ W2, const float* __restrict__ bias,
    float* __restrict__ y2, float* __restrict__ s2, float* __restrict__ sq2)
{
    __shared__ float ys[32][DD2];
    const int row0 = blockIdx.x * 32;
    const int tid  = threadIdx.x;
    for (int idx = tid; idx < 32 * DD2; idx += 256) {
        int r = idx >> 8, k = idx & 255;
        float v = fmaf(y1[(size_t)row0 * DD2 + idx], a1[k], c1[k]);
        ys[r][k] = fmaxf(v, 0.f);
    }
    __syncthreads();
    const int cg = tid & 31, rg = tid >> 5;
    const int c0 = cg * 4, r0 = rg * 4;
    float acc[4][4] = {};
    #pragma unroll 4
    for (int k4 = 0; k4 < 64; ++k4) {
        const int k = k4 * 4;
        const float4 b0 = *(const float4*)&W2[(k + 0) * DD + c0];
        const float4 b1 = *(const float4*)&W2[(k + 1) * DD + c0];
        const float4 b2 = *(const float4*)&W2[(k + 2) * DD + c0];
        const float4 b3 = *(const float4*)&W2[(k + 3) * DD + c0];
        #pragma unroll
        for (int r = 0; r < 4; ++r) {
            const float4 av = *(const float4*)&ys[r0 + r][k];
            fma4x4(av, b0, b1, b2, b3, acc[r]);
        }
    }
    const float4 bb = *(const float4*)&bias[c0];
    float ps[4] = {}, pq[4] = {};
    #pragma unroll
    for (int r = 0; r < 4; ++r) {
        float4 v;
        v.x = acc[r][0] + bb.x; v.y = acc[r][1] + bb.y;
        v.z = acc[r][2] + bb.z; v.w = acc[r][3] + bb.w;
        *(float4*)&y2[(size_t)(row0 + r0 + r) * DD + c0] = v;
        ps[0] += v.x; pq[0] += v.x * v.x;
        ps[1] += v.y; pq[1] += v.y * v.y;
        ps[2] += v.z; pq[2] += v.z * v.z;
        ps[3] += v.w; pq[3] += v.w * v.w;
    }
    __shared__ float redS[8][DD];
    __shared__ float redQ[8][DD];
    #pragma unroll
    for (int i = 0; i < 4; ++i) { redS[rg][c0 + i] = ps[i]; redQ[rg][c0 + i] = pq[i]; }
    __syncthreads();
    if (tid < DD) {
        float s = 0.f, q = 0.f;
        #pragma unroll
        for (int gi = 0; gi < 8; ++gi) { s += redS[gi][tid]; q += redQ[gi][tid]; }
        fadd_atomic(&s2[tid], s);
        fadd_atomic(&sq2[tid], q);
    }
}

// h = relu(bn(y2)) in place (layer 0 only)
__global__ void bn_relu_kernel(float* __restrict__ y2h, const float* __restrict__ a2,
                               const float* __restrict__ c2, int n4)
{
    int i = blockIdx.x * blockDim.x + threadIdx.x;
    const int stride = gridDim.x * blockDim.x;
    float4* p = (float4*)y2h;
    for (; i < n4; i += stride) {
        float4 v = p[i];
        const int d0 = (i & 31) * 4;
        v.x = fmaxf(fmaf(v.x, a2[d0 + 0], c2[d0 + 0]), 0.f);
        v.y = fmaxf(fmaf(v.y, a2[d0 + 1], c2[d0 + 1]), 0.f);
        v.z = fmaxf(fmaf(v.z, a2[d0 + 2], c2[d0 + 2]), 0.f);
        v.w = fmaxf(fmaf(v.w, a2[d0 + 3], c2[d0 + 3]), 0.f);
        p[i] = v;
    }
}

// final layer: out[g] = mean over contiguous node range of bn(y2)  (one wave/graph)
__global__ __launch_bounds__(256) void pool_kernel(
    const float* __restrict__ y2, const float* __restrict__ a2, const float* __restrict__ c2,
    const int* __restrict__ gstart, float* __restrict__ out)
{
    const int g = blockIdx.x * 4 + (threadIdx.x >> 6);
    if (g >= NG) return;
    const int lane = threadIdx.x & 63;
    const int s = gstart[g], t = gstart[g + 1];
    float a0 = 0.f, a1 = 0.f;
    for (int n = s; n < t; ++n) {
        const float2 v = *(const float2*)&y2[(size_t)n * DD + lane * 2];
        a0 += v.x; a1 += v.y;
    }
    const int d0 = lane * 2;
    float2 o;
    if (t > s) {
        const float inv = 1.0f / (float)(t - s);
        o.x = fmaf(a2[d0 + 0], a0 * inv, c2[d0 + 0]);
        o.y = fmaf(a2[d0 + 1], a1 * inv, c2[d0 + 1]);
    } else {
        o.x = 0.f; o.y = 0.f;
    }
    *(float2*)&out[(size_t)g * DD + d0] = o;
}

// ---------------- launch ----------------------------------------------------

extern "C" void kernel_launch(void* const* d_in, const int* in_sizes, int n_in,
                              void* d_out, int out_size, void* d_ws, size_t ws_size,
                              hipStream_t stream)
{
    (void)in_sizes; (void)n_in; (void)out_size; (void)ws_size;
    const float* x     = (const float*)d_in[0];
    const float* ea    = (const float*)d_in[1];
    const int*   src   = (const int*)d_in[2];
    const int*   dst   = (const int*)d_in[3];
    const int*   batch = (const int*)d_in[4];
    const float* W_emb = (const float*)d_in[5];
    const float* b_emb = (const float*)d_in[6];

    char* ws = (char*)d_ws;
    float* zbuf = (float*)ws;                                   ws += (size_t)NN * DD * 4;   // 51.2MB
    float* hbuf = (float*)ws;                                   ws += (size_t)NN * DD * 4;   // 51.2MB
    // shared region: msg (bf16 [E,128] = 153.6MB) and y1 (f32 [N,256] = 102.4MB)
    // are live at disjoint times within a layer.
    ushort* msgb = (ushort*)ws;
    float*  y1   = (float*)ws;                                  ws += (size_t)NE * DD * 2;   // 153.6MB
    int* deg   = (int*)ws;                                      ws += (size_t)NN * 4;
    int* offs  = (int*)ws;                                      ws += (size_t)(NN + 1) * 4;
    int* csr   = (int*)ws;                                      ws += (size_t)NE * 4;
    int* csums = (int*)ws;                                      ws += 128 * 4;
    int* gstart= (int*)ws;                                      ws += (size_t)(NG + 1) * 4;
    float* st  = (float*)ws;
    float* s1 = st,        *sq1 = st + 256, *a1 = st + 512,  *c1 = st + 768;
    float* s2 = st + 1024, *sq2 = st + 1152, *a2 = st + 1280, *c2 = st + 1408;
    float* out = (float*)d_out;

    const int NCHUNK = (NN + 1023) / 1024;   // 98

    // --- CSR build (graph constant across layers) ---
    hipMemsetAsync(deg, 0, (size_t)NN * 4, stream);
    hist_kernel<<<(NE + 255) / 256, 256, 0, stream>>>(dst, deg);
    scan_chunk_kernel<<<NCHUNK, 256, 0, stream>>>(deg, offs, csums);
    scan_tops_kernel<<<1, 1, 0, stream>>>(csums, offs, NCHUNK);
    scan_add_kernel<<<(NN + 255) / 256, 256, 0, stream>>>(offs, csums);
    hipMemsetAsync(deg, 0, (size_t)NN * 4, stream);              // reuse as cursor
    scatter_kernel<<<(NE + 255) / 256, 256, 0, stream>>>(dst, offs, deg, csr);
    gstart_kernel<<<(NN + 256) / 256, 256, 0, stream>>>(batch, gstart);

    embed_kernel<<<NN / 4, 128, 0, stream>>>(x, W_emb, b_emb, hbuf);

    for (int layer = 0; layer < 2; ++layer) {
        const float* const* L = (const float* const*)(d_in + 7 + layer * 10);
        const float* We = L[0]; const float* be  = L[1];
        const float* W1 = L[2]; const float* b1  = L[3];
        const float* g1 = L[4]; const float* bb1 = L[5];
        const float* W2 = L[6]; const float* b2  = L[7];
        const float* go = L[8]; const float* bo  = L[9];

        edge_gemm_kernel<<<NE / 32, 256, 0, stream>>>(ea, We, be, src, hbuf, msgb);
        agg_kernel<<<NN / 4, 256, 0, stream>>>(offs, csr, msgb, hbuf, zbuf);

        hipMemsetAsync(s1, 0, 512 * sizeof(float), stream);
        hipMemsetAsync(s2, 0, 256 * sizeof(float), stream);
        mlp1_kernel<<<NN / 16, 256, 0, stream>>>(zbuf, W1, b1, y1, s1, sq1);
        finalize_kernel<<<1, 256, 0, stream>>>(s1, sq1, g1, bb1, a1, c1, DD2, 1.0f / NN);
        mlp2_kernel<<<NN / 32, 256, 0, stream>>>(y1, a1, c1, W2, b2, hbuf, s2, sq2);
        finalize_kernel<<<1, 128, 0, stream>>>(s2, sq2, go, bo, a2, c2, DD, 1.0f / NN);

        if (layer == 0) {
            bn_relu_kernel<<<2048, 256, 0, stream>>>(hbuf, a2, c2, NN * DD / 4);
        } else {
            pool_kernel<<<NG / 4, 256, 0, stream>>>(hbuf, a2, c2, gstart, out);
        }
    }
}

// Round 3
// 1227.690 us; speedup vs baseline: 3.3323x; 2.4326x over previous
//
#include <hip/hip_runtime.h>
#include <cstddef>

#define NN  100000
#define NE  600000
#define NG  4096
#define DIN 73
#define DE  101
#define DD  128
#define DD2 256
#define NP  100096   // NN padded to 256-row tiles (391 blocks)
#define EP  600064   // NE padded to 256-row tiles (2344 blocks)

typedef unsigned int uint;
typedef unsigned short ushort;
typedef __attribute__((ext_vector_type(8))) short bf16x8;
typedef __attribute__((ext_vector_type(4))) float f32x4;

__device__ __forceinline__ void fadd_atomic(float* p, float v) { unsafeAtomicAdd(p, v); }

__device__ __forceinline__ ushort f2bf(float f) {   // RNE f32->bf16
    uint u = __float_as_uint(f);
    uint r = (u + 0x7fffu + ((u >> 16) & 1u)) >> 16;
    return (ushort)r;
}
__device__ __forceinline__ float bf2f(ushort u) { return __uint_as_float(((uint)u) << 16); }

// ---------------- CSR build (once per call) ---------------------------------

__global__ void hist_kernel(const int* __restrict__ dst, int* __restrict__ deg) {
    int e = blockIdx.x * blockDim.x + threadIdx.x;
    if (e < NE) atomicAdd(&deg[dst[e]], 1);
}

__global__ __launch_bounds__(256) void scan_chunk_kernel(
    const int* __restrict__ deg, int* __restrict__ offs, int* __restrict__ csums)
{
    const int b = blockIdx.x, t = threadIdx.x;
    const int base = b * 1024 + t * 4;
    int v[4];
    #pragma unroll
    for (int i = 0; i < 4; ++i) v[i] = (base + i < NN) ? deg[base + i] : 0;
    int tsum = v[0] + v[1] + v[2] + v[3];
    const int lane = t & 63, w = t >> 6;
    int x = tsum;
    #pragma unroll
    for (int d = 1; d < 64; d <<= 1) {
        int y = __shfl_up(x, d, 64);
        if (lane >= d) x += y;
    }
    __shared__ int wsum[4];
    if (lane == 63) wsum[w] = x;
    __syncthreads();
    int woff = 0;
    for (int i = 0; i < w; ++i) woff += wsum[i];
    int run = woff + x - tsum;
    #pragma unroll
    for (int i = 0; i < 4; ++i) {
        if (base + i < NN) offs[base + i] = run;
        run += v[i];
    }
    if (t == 255) csums[b] = woff + x;
}

__global__ void scan_tops_kernel(int* __restrict__ csums, int* __restrict__ offs, int nchunks) {
    if (threadIdx.x == 0 && blockIdx.x == 0) {
        int run = 0;
        for (int i = 0; i < nchunks; ++i) { int c = csums[i]; csums[i] = run; run += c; }
        offs[NN] = run;
    }
}

__global__ void scan_add_kernel(int* __restrict__ offs, const int* __restrict__ csums) {
    int i = blockIdx.x * blockDim.x + threadIdx.x;
    if (i < NN) offs[i] += csums[i >> 10];
}

__global__ void scatter_kernel(const int* __restrict__ dst, const int* __restrict__ offs,
                               int* __restrict__ cursor, int* __restrict__ csr)
{
    int e = blockIdx.x * blockDim.x + threadIdx.x;
    if (e >= NE) return;
    int d = dst[e];
    int pos = offs[d] + atomicAdd(&cursor[d], 1);
    csr[pos] = e;
}

__global__ void gstart_kernel(const int* __restrict__ batch, int* __restrict__ gstart) {
    int n = blockIdx.x * blockDim.x + threadIdx.x;
    if (n > NN) return;
    if (n == NN) {
        for (int g = batch[NN - 1] + 1; g <= NG; ++g) gstart[g] = NN;
        return;
    }
    int b = batch[n];
    int pb = (n == 0) ? -1 : batch[n - 1];
    for (int g = pb + 1; g <= b; ++g) gstart[g] = n;
}

// ---------------- conversions ----------------------------------------------

// ea f32 [E,101] -> bf16 [EP,128], zero-padded cols
__global__ __launch_bounds__(256) void cvt_ea_kernel(const float* __restrict__ ea,
                                                     ushort* __restrict__ eab)
{
    const int t = threadIdx.x;
    const int r = blockIdx.x * 8 + (t >> 5);
    if (r >= NE) return;
    const int c = (t & 31) * 4;
    ushort4 o;
    o.x = (c + 0 < DE) ? f2bf(ea[(size_t)r * DE + c + 0]) : (ushort)0;
    o.y = (c + 1 < DE) ? f2bf(ea[(size_t)r * DE + c + 1]) : (ushort)0;
    o.z = (c + 2 < DE) ? f2bf(ea[(size_t)r * DE + c + 2]) : (ushort)0;
    o.w = (c + 3 < DE) ? f2bf(ea[(size_t)r * DE + c + 3]) : (ushort)0;
    *(ushort4*)&eab[(size_t)r * 128 + c] = o;
}

// in f32 [Kin,Nn] -> out bf16 [Nn][Kp] (transposed, zero-padded k)
__global__ void cvt_wt_kernel(const float* __restrict__ in, ushort* __restrict__ out,
                              int Kin, int Nn, int Kp)
{
    const int n = blockIdx.x;
    for (int k = threadIdx.x; k < Kp; k += blockDim.x)
        out[(size_t)n * Kp + k] = (k < Kin) ? f2bf(in[(size_t)k * Nn + n]) : (ushort)0;
}

// ---------------- MFMA GEMM core -------------------------------------------
// D[n][m] = sum_k Wt[n][k] * X[m][k].  Wave tile: 64 m-rows x 128 n-cols.
// Frag layout (16x16x32 bf16): operand lane l: row/col = l&15, k = (l>>4)*8+j.
// C/D: "col"(m) = l&15, "row"(n) = (l>>4)*4 + reg.
template<int K>
__device__ __forceinline__ void mma_core(const ushort* __restrict__ Wt,
                                         const ushort* __restrict__ X,
                                         int n0, int m0, f32x4 acc[4][8])
{
    const int lane = threadIdx.x & 63;
    const int l15 = lane & 15, grp = lane >> 4;
    const size_t aoff = (size_t)(n0 + l15) * K + grp * 8;
    const size_t boff = (size_t)(m0 + l15) * K + grp * 8;
    #pragma unroll
    for (int kk = 0; kk < K / 32; ++kk) {
        bf16x8 a[8], b[4];
        #pragma unroll
        for (int nf = 0; nf < 8; ++nf)
            a[nf] = *(const bf16x8*)(Wt + aoff + (size_t)nf * 16 * K + kk * 32);
        #pragma unroll
        for (int mf = 0; mf < 4; ++mf)
            b[mf] = *(const bf16x8*)(X + boff + (size_t)mf * 16 * K + kk * 32);
        #pragma unroll
        for (int mf = 0; mf < 4; ++mf)
            #pragma unroll
            for (int nf = 0; nf < 8; ++nf)
                acc[mf][nf] = __builtin_amdgcn_mfma_f32_16x16x32_bf16(a[nf], b[mf], acc[mf][nf], 0, 0, 0);
    }
}

__device__ __forceinline__ void acc_zero(f32x4 acc[4][8]) {
    #pragma unroll
    for (int i = 0; i < 4; ++i)
        #pragma unroll
        for (int j = 0; j < 8; ++j)
            acc[i][j] = (f32x4){0.f, 0.f, 0.f, 0.f};
}

// edge: msg = relu(ea@We + be + h[src]) -> bf16 msgb [EP,128]
__global__ __launch_bounds__(256) void edge_gemm_kernel(
    const ushort* __restrict__ eab, const ushort* __restrict__ Wt,
    const float* __restrict__ be, const int* __restrict__ src,
    const float* __restrict__ h, ushort* __restrict__ msg)
{
    f32x4 acc[4][8];
    acc_zero(acc);
    const int e0 = blockIdx.x * 256 + (threadIdx.x >> 6) * 64;
    mma_core<128>(Wt, eab, 0, e0, acc);
    const int lane = threadIdx.x & 63, l15 = lane & 15, grp = lane >> 4;
    float4 bev[8];
    #pragma unroll
    for (int nf = 0; nf < 8; ++nf) bev[nf] = *(const float4*)&be[nf * 16 + grp * 4];
    #pragma unroll
    for (int mf = 0; mf < 4; ++mf) {
        const int e = e0 + mf * 16 + l15;
        const int sn = src[min(e, NE - 1)];
        const float* hp = &h[(size_t)sn * 128];
        #pragma unroll
        for (int nf = 0; nf < 8; ++nf) {
            const int nb = nf * 16 + grp * 4;
            const float4 hv = *(const float4*)&hp[nb];
            ushort4 o;
            o.x = f2bf(fmaxf(acc[mf][nf][0] + bev[nf].x + hv.x, 0.f));
            o.y = f2bf(fmaxf(acc[mf][nf][1] + bev[nf].y + hv.y, 0.f));
            o.z = f2bf(fmaxf(acc[mf][nf][2] + bev[nf].z + hv.z, 0.f));
            o.w = f2bf(fmaxf(acc[mf][nf][3] + bev[nf].w + hv.w, 0.f));
            *(ushort4*)&msg[(size_t)e * 128 + nb] = o;
        }
    }
}

// mlp1: y1 = z@W1 + b1 -> bf16 [NP,256]
__global__ __launch_bounds__(256) void mlp1_gemm_kernel(
    const ushort* __restrict__ z, const ushort* __restrict__ Wt,
    const float* __restrict__ bias, ushort* __restrict__ y)
{
    f32x4 acc[4][8];
    acc_zero(acc);
    const int m0 = blockIdx.x * 256 + (threadIdx.x >> 6) * 64;
    const int n0 = blockIdx.y * 128;
    mma_core<128>(Wt, z, n0, m0, acc);
    const int lane = threadIdx.x & 63, l15 = lane & 15, grp = lane >> 4;
    #pragma unroll
    for (int nf = 0; nf < 8; ++nf) {
        const int nb = n0 + nf * 16 + grp * 4;
        const float4 bv = *(const float4*)&bias[nb];
        #pragma unroll
        for (int mf = 0; mf < 4; ++mf) {
            const size_t m = m0 + mf * 16 + l15;
            ushort4 o;
            o.x = f2bf(acc[mf][nf][0] + bv.x);
            o.y = f2bf(acc[mf][nf][1] + bv.y);
            o.z = f2bf(acc[mf][nf][2] + bv.z);
            o.w = f2bf(acc[mf][nf][3] + bv.w);
            *(ushort4*)&y[m * 256 + nb] = o;
        }
    }
}

// mlp2: y2 = y1r@W2 + b2 -> f32 [NP,128]
__global__ __launch_bounds__(256) void mlp2_gemm_kernel(
    const ushort* __restrict__ y1, const ushort* __restrict__ Wt,
    const float* __restrict__ bias, float* __restrict__ y2)
{
    f32x4 acc[4][8];
    acc_zero(acc);
    const int m0 = blockIdx.x * 256 + (threadIdx.x >> 6) * 64;
    mma_core<256>(Wt, y1, 0, m0, acc);
    const int lane = threadIdx.x & 63, l15 = lane & 15, grp = lane >> 4;
    #pragma unroll
    for (int nf = 0; nf < 8; ++nf) {
        const int nb = nf * 16 + grp * 4;
        const float4 bv = *(const float4*)&bias[nb];
        #pragma unroll
        for (int mf = 0; mf < 4; ++mf) {
            const size_t m = m0 + mf * 16 + l15;
            float4 o;
            o.x = acc[mf][nf][0] + bv.x;
            o.y = acc[mf][nf][1] + bv.y;
            o.z = acc[mf][nf][2] + bv.z;
            o.w = acc[mf][nf][3] + bv.w;
            *(float4*)&y2[m * 128 + nb] = o;
        }
    }
}

// ---------------- elementwise / reduction kernels ---------------------------

// h = x @ W_emb + b_emb (f32, runs once)
__global__ __launch_bounds__(128) void embed_kernel(
    const float* __restrict__ x, const float* __restrict__ W,
    const float* __restrict__ b, float* __restrict__ h)
{
    __shared__ float xs[4][DIN];
    const int n0 = blockIdx.x * 4;
    const int d  = threadIdx.x;
    for (int idx = d; idx < 4 * DIN; idx += 128) {
        int r = idx / DIN, c = idx - r * DIN;
        xs[r][c] = x[(size_t)n0 * DIN + idx];
    }
    __syncthreads();
    float bb = b[d];
    float a0 = bb, a1 = bb, a2 = bb, a3 = bb;
    for (int k = 0; k < DIN; ++k) {
        float w = W[k * DD + d];
        a0 = fmaf(xs[0][k], w, a0);
        a1 = fmaf(xs[1][k], w, a1);
        a2 = fmaf(xs[2][k], w, a2);
        a3 = fmaf(xs[3][k], w, a3);
    }
    h[(size_t)(n0 + 0) * DD + d] = a0;
    h[(size_t)(n0 + 1) * DD + d] = a1;
    h[(size_t)(n0 + 2) * DD + d] = a2;
    h[(size_t)(n0 + 3) * DD + d] = a3;
}

// z_bf[n] = bf16(h[n] + sum msg[e])   one wave per node
__global__ __launch_bounds__(256) void agg_kernel(
    const int* __restrict__ offs, const int* __restrict__ csr,
    const ushort* __restrict__ msgb, const float* __restrict__ h,
    ushort* __restrict__ zb)
{
    const int n = blockIdx.x * 4 + (threadIdx.x >> 6);
    if (n >= NN) return;
    const int lane = threadIdx.x & 63;
    const int s = offs[n], t = offs[n + 1];
    float a0 = 0.f, a1 = 0.f;
    for (int i = s; i < t; ++i) {
        const int e = csr[i];
        const uint mv = *(const uint*)&msgb[(size_t)e * 128 + lane * 2];
        a0 += __uint_as_float(mv << 16);
        a1 += __uint_as_float(mv & 0xffff0000u);
    }
    const float2 hv = *(const float2*)&h[(size_t)n * 128 + lane * 2];
    ushort2 o;
    o.x = f2bf(hv.x + a0);
    o.y = f2bf(hv.y + a1);
    *(ushort2*)&zb[(size_t)n * 128 + lane * 2] = o;
}

// column sums/sumsq of y1_bf [NN,256]
__global__ __launch_bounds__(256) void colstats256_kernel(
    const ushort* __restrict__ y, float* __restrict__ s, float* __restrict__ q)
{
    const int t = threadIdx.x;
    const int cs = (t & 63) * 4, rg = t >> 6;
    const int r0 = blockIdx.x * 256;
    float ps0 = 0, ps1 = 0, ps2 = 0, ps3 = 0, pq0 = 0, pq1 = 0, pq2 = 0, pq3 = 0;
    for (int i = rg; i < 256; i += 4) {
        const int r = r0 + i;
        if (r >= NN) break;
        ushort4 u = *(const ushort4*)&y[(size_t)r * 256 + cs];
        float f0 = bf2f(u.x), f1 = bf2f(u.y), f2v = bf2f(u.z), f3 = bf2f(u.w);
        ps0 += f0; pq0 += f0 * f0;
        ps1 += f1; pq1 += f1 * f1;
        ps2 += f2v; pq2 += f2v * f2v;
        ps3 += f3; pq3 += f3 * f3;
    }
    __shared__ float SS[4][256], SQ[4][256];
    SS[rg][cs + 0] = ps0; SS[rg][cs + 1] = ps1; SS[rg][cs + 2] = ps2; SS[rg][cs + 3] = ps3;
    SQ[rg][cs + 0] = pq0; SQ[rg][cs + 1] = pq1; SQ[rg][cs + 2] = pq2; SQ[rg][cs + 3] = pq3;
    __syncthreads();
    if (rg == 0) {
        #pragma unroll
        for (int j = 0; j < 4; ++j) {
            const int c = cs + j;
            fadd_atomic(&s[c], SS[0][c] + SS[1][c] + SS[2][c] + SS[3][c]);
            fadd_atomic(&q[c], SQ[0][c] + SQ[1][c] + SQ[2][c] + SQ[3][c]);
        }
    }
}

// column sums/sumsq of y2 f32 [NN,128]
__global__ __launch_bounds__(256) void colstats128_kernel(
    const float* __restrict__ y, float* __restrict__ s, float* __restrict__ q)
{
    const int t = threadIdx.x;
    const int cs = (t & 31) * 4, rg = t >> 5;
    const int r0 = blockIdx.x * 256;
    float ps0 = 0, ps1 = 0, ps2 = 0, ps3 = 0, pq0 = 0, pq1 = 0, pq2 = 0, pq3 = 0;
    for (int i = rg; i < 256; i += 8) {
        const int r = r0 + i;
        if (r >= NN) break;
        float4 v = *(const float4*)&y[(size_t)r * 128 + cs];
        ps0 += v.x; pq0 += v.x * v.x;
        ps1 += v.y; pq1 += v.y * v.y;
        ps2 += v.z; pq2 += v.z * v.z;
        ps3 += v.w; pq3 += v.w * v.w;
    }
    __shared__ float SS[8][128], SQ[8][128];
    SS[rg][cs + 0] = ps0; SS[rg][cs + 1] = ps1; SS[rg][cs + 2] = ps2; SS[rg][cs + 3] = ps3;
    SQ[rg][cs + 0] = pq0; SQ[rg][cs + 1] = pq1; SQ[rg][cs + 2] = pq2; SQ[rg][cs + 3] = pq3;
    __syncthreads();
    if (rg == 0) {
        #pragma unroll
        for (int j = 0; j < 4; ++j) {
            const int c = cs + j;
            float sv = 0, qv = 0;
            #pragma unroll
            for (int g = 0; g < 8; ++g) { sv += SS[g][c]; qv += SQ[g][c]; }
            fadd_atomic(&s[c], sv);
            fadd_atomic(&q[c], qv);
        }
    }
}

__global__ void finalize_kernel(const float* __restrict__ s, const float* __restrict__ sq,
                                const float* __restrict__ g, const float* __restrict__ bb,
                                float* __restrict__ a, float* __restrict__ c,
                                int dim, float invN)
{
    int d = blockIdx.x * blockDim.x + threadIdx.x;
    if (d >= dim) return;
    float m  = s[d] * invN;
    float v  = sq[d] * invN - m * m;
    float rs = rsqrtf(v + 1e-5f);
    float ai = g[d] * rs;
    a[d] = ai;
    c[d] = bb[d] - m * ai;
}

// y1_bf = bf16(relu(bn1(y1_bf))) in place, rows < NN
__global__ void bnrelu_bf_kernel(ushort* __restrict__ y, const float* __restrict__ a,
                                 const float* __restrict__ c)
{
    int i = blockIdx.x * blockDim.x + threadIdx.x;
    const int stride = gridDim.x * blockDim.x;
    for (; i < NN * 64; i += stride) {
        const int cb = (i & 63) * 4;
        ushort4 u = *(const ushort4*)&y[(size_t)i * 4];
        const float4 av = *(const float4*)&a[cb];
        const float4 cv = *(const float4*)&c[cb];
        ushort4 o;
        o.x = f2bf(fmaxf(fmaf(bf2f(u.x), av.x, cv.x), 0.f));
        o.y = f2bf(fmaxf(fmaf(bf2f(u.y), av.y, cv.y), 0.f));
        o.z = f2bf(fmaxf(fmaf(bf2f(u.z), av.z, cv.z), 0.f));
        o.w = f2bf(fmaxf(fmaf(bf2f(u.w), av.w, cv.w), 0.f));
        *(ushort4*)&y[(size_t)i * 4] = o;
    }
}

// h = relu(bn(y2)) in place f32 (layer 0)
__global__ void bn_relu_kernel(float* __restrict__ y2h, const float* __restrict__ a2,
                               const float* __restrict__ c2, int n4)
{
    int i = blockIdx.x * blockDim.x + threadIdx.x;
    const int stride = gridDim.x * blockDim.x;
    float4* p = (float4*)y2h;
    for (; i < n4; i += stride) {
        float4 v = p[i];
        const int d0 = (i & 31) * 4;
        v.x = fmaxf(fmaf(v.x, a2[d0 + 0], c2[d0 + 0]), 0.f);
        v.y = fmaxf(fmaf(v.y, a2[d0 + 1], c2[d0 + 1]), 0.f);
        v.z = fmaxf(fmaf(v.z, a2[d0 + 2], c2[d0 + 2]), 0.f);
        v.w = fmaxf(fmaf(v.w, a2[d0 + 3], c2[d0 + 3]), 0.f);
        p[i] = v;
    }
}

// final: out[g] = bn(mean over node range of y2)
__global__ __launch_bounds__(256) void pool_kernel(
    const float* __restrict__ y2, const float* __restrict__ a2, const float* __restrict__ c2,
    const int* __restrict__ gstart, float* __restrict__ out)
{
    const int g = blockIdx.x * 4 + (threadIdx.x >> 6);
    if (g >= NG) return;
    const int lane = threadIdx.x & 63;
    const int s = gstart[g], t = gstart[g + 1];
    float a0 = 0.f, a1 = 0.f;
    for (int n = s; n < t; ++n) {
        const float2 v = *(const float2*)&y2[(size_t)n * 128 + lane * 2];
        a0 += v.x; a1 += v.y;
    }
    const int d0 = lane * 2;
    float2 o;
    if (t > s) {
        const float inv = 1.0f / (float)(t - s);
        o.x = fmaf(a2[d0 + 0], a0 * inv, c2[d0 + 0]);
        o.y = fmaf(a2[d0 + 1], a1 * inv, c2[d0 + 1]);
    } else {
        o.x = 0.f; o.y = 0.f;
    }
    *(float2*)&out[(size_t)g * 128 + d0] = o;
}

// ---------------- launch ----------------------------------------------------

extern "C" void kernel_launch(void* const* d_in, const int* in_sizes, int n_in,
                              void* d_out, int out_size, void* d_ws, size_t ws_size,
                              hipStream_t stream)
{
    (void)in_sizes; (void)n_in; (void)out_size; (void)ws_size;
    const float* x     = (const float*)d_in[0];
    const float* ea    = (const float*)d_in[1];
    const int*   src   = (const int*)d_in[2];
    const int*   dst   = (const int*)d_in[3];
    const int*   batch = (const int*)d_in[4];
    const float* W_emb = (const float*)d_in[5];
    const float* b_emb = (const float*)d_in[6];

    char* ws = (char*)d_ws;
    auto alloc = [&](size_t bytes) { void* p = ws; ws += (bytes + 255) & ~(size_t)255; return p; };

    float*  hbuf = (float*) alloc((size_t)NP * 128 * 4);   // 51.2 MB  h / y2
    ushort* zb   = (ushort*)alloc((size_t)NP * 128 * 2);   // 25.6 MB  z bf16
    ushort* eab  = (ushort*)alloc((size_t)EP * 128 * 2);   // 153.6 MB ea bf16 (both layers)
    ushort* big  = (ushort*)alloc((size_t)EP * 128 * 2);   // 153.6 MB msgb ∪ y1_bf
    ushort* msgb = big;
    ushort* y1b  = big;        // [NP,256] bf16 = 51.2 MB, live after msgb is dead
    int* deg    = (int*)alloc((size_t)NN * 4);
    int* offs   = (int*)alloc((size_t)(NN + 1) * 4);
    int* csr    = (int*)alloc((size_t)NE * 4);
    int* csums  = (int*)alloc(128 * 4);
    int* gstart = (int*)alloc((size_t)(NG + 1) * 4);
    ushort* Wet[2], *W1t[2], *W2t[2];
    for (int l = 0; l < 2; ++l) {
        Wet[l] = (ushort*)alloc(128 * 128 * 2);
        W1t[l] = (ushort*)alloc(256 * 128 * 2);
        W2t[l] = (ushort*)alloc(128 * 256 * 2);
    }
    float* st = (float*)alloc(2048 * 4);
    float* s1 = st,        *sq1 = st + 256, *a1 = st + 512,  *c1 = st + 768;
    float* s2 = st + 1024, *sq2 = st + 1152, *a2 = st + 1280, *c2 = st + 1408;
    float* out = (float*)d_out;

    const int NCHUNK = (NN + 1023) / 1024;

    // CSR + graph boundaries (constant across layers)
    hipMemsetAsync(deg, 0, (size_t)NN * 4, stream);
    hist_kernel<<<(NE + 255) / 256, 256, 0, stream>>>(dst, deg);
    scan_chunk_kernel<<<NCHUNK, 256, 0, stream>>>(deg, offs, csums);
    scan_tops_kernel<<<1, 1, 0, stream>>>(csums, offs, NCHUNK);
    scan_add_kernel<<<(NN + 255) / 256, 256, 0, stream>>>(offs, csums);
    hipMemsetAsync(deg, 0, (size_t)NN * 4, stream);
    scatter_kernel<<<(NE + 255) / 256, 256, 0, stream>>>(dst, offs, deg, csr);
    gstart_kernel<<<(NN + 256) / 256, 256, 0, stream>>>(batch, gstart);

    // one-time conversions
    cvt_ea_kernel<<<(NE + 7) / 8, 256, 0, stream>>>(ea, eab);
    for (int l = 0; l < 2; ++l) {
        const float* const* L = (const float* const*)(d_in + 7 + l * 10);
        cvt_wt_kernel<<<128, 128, 0, stream>>>(L[0], Wet[l], 101, 128, 128);  // We
        cvt_wt_kernel<<<256, 128, 0, stream>>>(L[2], W1t[l], 128, 256, 128);  // W1
        cvt_wt_kernel<<<128, 128, 0, stream>>>(L[6], W2t[l], 256, 128, 256);  // W2
    }

    embed_kernel<<<NN / 4, 128, 0, stream>>>(x, W_emb, b_emb, hbuf);

    for (int layer = 0; layer < 2; ++layer) {
        const float* const* L = (const float* const*)(d_in + 7 + layer * 10);
        const float* be  = L[1];
        const float* b1  = L[3];
        const float* g1  = L[4]; const float* bb1 = L[5];
        const float* b2  = L[7];
        const float* go  = L[8]; const float* bo  = L[9];

        edge_gemm_kernel<<<EP / 256, 256, 0, stream>>>(eab, Wet[layer], be, src, hbuf, msgb);
        agg_kernel<<<NN / 4, 256, 0, stream>>>(offs, csr, msgb, hbuf, zb);

        hipMemsetAsync(s1, 0, 512 * sizeof(float), stream);
        hipMemsetAsync(s2, 0, 256 * sizeof(float), stream);

        mlp1_gemm_kernel<<<dim3(NP / 256, 2), 256, 0, stream>>>(zb, W1t[layer], b1, y1b);
        colstats256_kernel<<<NP / 256, 256, 0, stream>>>(y1b, s1, sq1);
        finalize_kernel<<<1, 256, 0, stream>>>(s1, sq1, g1, bb1, a1, c1, 256, 1.0f / NN);
        bnrelu_bf_kernel<<<2048, 256, 0, stream>>>(y1b, a1, c1);
        mlp2_gemm_kernel<<<NP / 256, 256, 0, stream>>>(y1b, W2t[layer], b2, hbuf);
        colstats128_kernel<<<NP / 256, 256, 0, stream>>>(hbuf, s2, sq2);
        finalize_kernel<<<1, 128, 0, stream>>>(s2, sq2, go, bo, a2, c2, 128, 1.0f / NN);

        if (layer == 0) {
            bn_relu_kernel<<<2048, 256, 0, stream>>>(hbuf, a2, c2, NN * 128 / 4);
        } else {
            pool_kernel<<<NG / 4, 256, 0, stream>>>(hbuf, a2, c2, gstart, out);
        }
    }
}